// Round 6
// baseline (271.307 us; speedup 1.0000x reference)
//
#include <hip/hip_runtime.h>
#include <hip/hip_bf16.h>
#include <math.h>

#define B_  16
#define N_  16
#define T_  48
#define C_  512
#define H_  8
#define HD_ 64
#define L_  768
#define BL_ 12288

typedef __attribute__((ext_vector_type(8))) short b16x8;
typedef __attribute__((ext_vector_type(4))) short b16x4;
typedef __attribute__((ext_vector_type(4))) float f32x4;

__device__ __forceinline__ short f2b(float f) {
  __hip_bfloat16 h = __float2bfloat16(f);
  return *reinterpret_cast<short*>(&h);
}

// ---------------------------------------------------------------------------
// cast x (fp32) -> bf16
// ---------------------------------------------------------------------------
__global__ __launch_bounds__(256) void cast_x_kernel(
    const float* __restrict__ x, short* __restrict__ xb, int n8)
{
  int i = blockIdx.x * 256 + threadIdx.x;
  if (i < n8) {
    const float4* src = (const float4*)(x + (size_t)i * 8);
    float4 a = src[0], b = src[1];
    short tmp[8] = {f2b(a.x), f2b(a.y), f2b(a.z), f2b(a.w),
                    f2b(b.x), f2b(b.y), f2b(b.z), f2b(b.w)};
    *(b16x8*)(xb + (size_t)i * 8) = *(b16x8*)tmp;
  }
}

// ---------------------------------------------------------------------------
// cast + transpose weights: WT[mat][n][k] = W[k][n], mat: 0=Wq 1=Wk 2=Wv 3=Wo
// ---------------------------------------------------------------------------
__global__ __launch_bounds__(256) void cast_w_kernel(
    const float* __restrict__ Wq, const float* __restrict__ Wk,
    const float* __restrict__ Wv, const float* __restrict__ Wo,
    short* __restrict__ WT)
{
  __shared__ float tile[32][33];
  int mat = blockIdx.z;
  const float* W = (mat == 0) ? Wq : (mat == 1) ? Wk : (mat == 2) ? Wv : Wo;
  int k0 = blockIdx.x * 32, n0 = blockIdx.y * 32;
  int tx = threadIdx.x, ty = threadIdx.y;     // 32 x 8
  for (int i = ty; i < 32; i += 8) tile[i][tx] = W[(size_t)(k0 + i) * 512 + n0 + tx];
  __syncthreads();
  short* dst = WT + (size_t)mat * 512 * 512;
  for (int i = ty; i < 32; i += 8)
    dst[(size_t)(n0 + i) * 512 + k0 + tx] = f2b(tile[tx][i]);
}

// ---------------------------------------------------------------------------
// QKV GEMM. Outputs in time-major attention layouts:
//   q2,k2: [b][h][t][n][d]   (16 particles of one timestep contiguous)
//   vT2  : [b][h][d][kt][kn] (PV K-dim kn contiguous per (d,kt))
// q scaled by 1/8.
// ---------------------------------------------------------------------------
__global__ __launch_bounds__(256) void qkv_kernel(
    const short* __restrict__ xb, const short* __restrict__ WT,
    short* __restrict__ q2, short* __restrict__ k2, short* __restrict__ vT2)
{
  __shared__ short As[128][32];
  __shared__ short Bs[128][32];
  int tid = threadIdx.x;
  int w = tid >> 6, lane = tid & 63, n16 = lane & 15, quad = lane >> 4;
  int bm = blockIdx.x, bn = blockIdx.y;
  int mat = bn >> 2;
  int ncol0 = (bn & 3) * 128;
  int row0 = bm * 128;
  const short* Wt = WT + (size_t)mat * 262144;
  float scale = (mat == 0) ? 0.125f : 1.0f;

  f32x4 zero4 = {0.f, 0.f, 0.f, 0.f};
  f32x4 acc[4][4];
  #pragma unroll
  for (int mt = 0; mt < 4; ++mt)
    #pragma unroll
    for (int nt = 0; nt < 4; ++nt) acc[mt][nt] = zero4;

  int srow = tid >> 1, sch = (tid & 1) * 16;
  const short* ga = xb + (size_t)(row0 + srow) * 512 + sch;
  const short* gb = Wt + (size_t)(ncol0 + srow) * 512 + sch;
  int wm = (w >> 1) * 64, wn = (w & 1) * 64;

  for (int kt = 0; kt < 16; ++kt) {
    b16x8 a0 = *(const b16x8*)(ga);
    b16x8 a1 = *(const b16x8*)(ga + 8);
    b16x8 b0 = *(const b16x8*)(gb);
    b16x8 b1 = *(const b16x8*)(gb + 8);
    ga += 32; gb += 32;
    __syncthreads();
    *(b16x8*)&As[srow][sch]     = a0;
    *(b16x8*)&As[srow][sch + 8] = a1;
    *(b16x8*)&Bs[srow][sch]     = b0;
    *(b16x8*)&Bs[srow][sch + 8] = b1;
    __syncthreads();
    b16x8 af[4], bf[4];
    #pragma unroll
    for (int mt = 0; mt < 4; ++mt) af[mt] = *(const b16x8*)&As[wm + mt * 16 + n16][quad * 8];
    #pragma unroll
    for (int nt = 0; nt < 4; ++nt) bf[nt] = *(const b16x8*)&Bs[wn + nt * 16 + n16][quad * 8];
    #pragma unroll
    for (int mt = 0; mt < 4; ++mt)
      #pragma unroll
      for (int nt = 0; nt < 4; ++nt)
        acc[mt][nt] = __builtin_amdgcn_mfma_f32_16x16x32_bf16(af[mt], bf[nt], acc[mt][nt], 0, 0, 0);
  }

  #pragma unroll
  for (int mt = 0; mt < 4; ++mt) {
    int rowb = row0 + wm + mt * 16 + quad * 4;   // global row, mult of 4
    int bb = rowb / 768;
    int l0 = rowb - bb * 768;
    int pn = l0 / 48;                             // particle
    int pt = l0 - pn * 48;                        // time (mult of 4, pt+3 < 48)
    #pragma unroll
    for (int nt = 0; nt < 4; ++nt) {
      int colg = ncol0 + wn + nt * 16 + n16;
      int hh = colg >> 6, d = colg & 63;
      if (mat == 2) {
        #pragma unroll
        for (int r = 0; r < 4; ++r)
          vT2[(((size_t)(bb * 8 + hh) * 64 + d) * 48 + pt + r) * 16 + pn] = f2b(acc[mt][nt][r]);
      } else {
        short* dst = (mat == 0) ? q2 : k2;
        #pragma unroll
        for (int r = 0; r < 4; ++r)
          dst[(((size_t)(bb * 8 + hh) * 48 + pt + r) * 16 + pn) * 64 + d] = f2b(acc[mt][nt][r] * scale);
      }
    }
  }
}

// ---------------------------------------------------------------------------
// Attention, time-major, ZERO LDS. Wave = (b,h, qt-pair {qt,47-qt}), 25
// balanced kt2 steps. S^T = K·Q^T so exp'd P sits directly in the A-frag
// layout of v_mfma_f32_16x16x16_bf16 (lane=qn, regs=kn) -> PV from registers.
// ---------------------------------------------------------------------------
__global__ __launch_bounds__(128) void attn_kernel(
    const short* __restrict__ q2, const short* __restrict__ k2,
    const short* __restrict__ vT2,
    const float* __restrict__ relT, const float* __restrict__ relP,
    short* __restrict__ yatt)
{
  int tid = threadIdx.x;
  int wv = tid >> 6, lane = tid & 63, n16 = lane & 15, quad = lane >> 4;
  int blk = blockIdx.x;
  int h = blk & 7;                  // XCD-locality
  int g = blk >> 3;
  int pg = g % 12, b = g / 12;
  int pair = pg * 2 + wv;           // 0..23
  int qtA = pair, qtB = 47 - pair;
  int nA = (qtA + 2) >> 1, nB = (qtB + 2) >> 1;   // nA + nB == 25

  // bias_p: lane regs hold kn = quad*4+r, lane col = qn = n16
  float bp4[4];
  #pragma unroll
  for (int r = 0; r < 4; ++r)
    bp4[r] = relP[((quad * 4 + r) - n16 + 15) * 8 + h];

  size_t bh = (size_t)(b * 8 + h);
  const short* qb = q2 + bh * 49152;
  const short* kb = k2 + bh * 49152;
  const short* vb = vT2 + bh * 49152;

  // Q B-frags (loaded once)
  b16x8 qA0 = *(const b16x8*)(qb + (qtA * 16 + n16) * 64 + quad * 8);
  b16x8 qA1 = *(const b16x8*)(qb + (qtA * 16 + n16) * 64 + quad * 8 + 32);
  b16x8 qB0 = *(const b16x8*)(qb + (qtB * 16 + n16) * 64 + quad * 8);
  b16x8 qB1 = *(const b16x8*)(qb + (qtB * 16 + n16) * 64 + quad * 8 + 32);

  f32x4 zero4 = {0.f, 0.f, 0.f, 0.f};
  f32x4 oA[4], oB[4];
  float psA = 0.f, psB = 0.f;
  #pragma unroll
  for (int nt = 0; nt < 4; ++nt) { oA[nt] = zero4; oB[nt] = zero4; }

  // time-bias scalar per tile: valid iff kt <= qt
  #define BT(kt, qt) ((kt) <= (qt) ? relT[((kt) - (qt) + 47) * 8 + h] : -1e30f)

  // prefetch step 0 (kt = 0,1)
  b16x8 kf[4];
  b16x4 vf[2][4];
  float btA[2], btB[2];
  #pragma unroll
  for (int t = 0; t < 2; ++t) {
    kf[2 * t]     = *(const b16x8*)(kb + (t * 16 + n16) * 64 + quad * 8);
    kf[2 * t + 1] = *(const b16x8*)(kb + (t * 16 + n16) * 64 + quad * 8 + 32);
    #pragma unroll
    for (int nt = 0; nt < 4; ++nt)
      vf[t][nt] = *(const b16x4*)(vb + ((nt * 16 + n16) * 48 + t) * 16 + quad * 4);
    btA[t] = BT(t, qtA); btB[t] = BT(t, qtB);
  }

  for (int kt2 = 0; kt2 < nB; ++kt2) {
    b16x8 nkf[4];
    b16x4 nvf[2][4];
    float nbtA[2], nbtB[2];
    if (kt2 + 1 < nB) {               // wave-uniform prefetch
      int kt0n = (kt2 + 1) * 2;
      #pragma unroll
      for (int t = 0; t < 2; ++t) {
        int kt = kt0n + t;
        nkf[2 * t]     = *(const b16x8*)(kb + (kt * 16 + n16) * 64 + quad * 8);
        nkf[2 * t + 1] = *(const b16x8*)(kb + (kt * 16 + n16) * 64 + quad * 8 + 32);
        #pragma unroll
        for (int nt = 0; nt < 4; ++nt)
          nvf[t][nt] = *(const b16x4*)(vb + ((nt * 16 + n16) * 48 + kt) * 16 + quad * 4);
        nbtA[t] = BT(kt, qtA); nbtB[t] = BT(kt, qtB);
      }
    }

    // ---- band B (always active) ----
    {
      f32x4 s0 = zero4, s1 = zero4;
      s0 = __builtin_amdgcn_mfma_f32_16x16x32_bf16(kf[0], qB0, s0, 0, 0, 0);
      s0 = __builtin_amdgcn_mfma_f32_16x16x32_bf16(kf[1], qB1, s0, 0, 0, 0);
      s1 = __builtin_amdgcn_mfma_f32_16x16x32_bf16(kf[2], qB0, s1, 0, 0, 0);
      s1 = __builtin_amdgcn_mfma_f32_16x16x32_bf16(kf[3], qB1, s1, 0, 0, 0);
      short p0[4], p1[4];
      #pragma unroll
      for (int r = 0; r < 4; ++r) {
        float e0 = __expf(s0[r] + btB[0] + bp4[r]);
        float e1 = __expf(s1[r] + btB[1] + bp4[r]);
        psB += e0 + e1;
        p0[r] = f2b(e0); p1[r] = f2b(e1);
      }
      b16x4 pf0 = *(b16x4*)p0, pf1 = *(b16x4*)p1;
      #pragma unroll
      for (int nt = 0; nt < 4; ++nt) {
        oB[nt] = __builtin_amdgcn_mfma_f32_16x16x16bf16_1k(pf0, vf[0][nt], oB[nt], 0, 0, 0);
        oB[nt] = __builtin_amdgcn_mfma_f32_16x16x16bf16_1k(pf1, vf[1][nt], oB[nt], 0, 0, 0);
      }
    }

    // ---- band A ----
    if (kt2 < nA) {                   // wave-uniform
      f32x4 s0 = zero4, s1 = zero4;
      s0 = __builtin_amdgcn_mfma_f32_16x16x32_bf16(kf[0], qA0, s0, 0, 0, 0);
      s0 = __builtin_amdgcn_mfma_f32_16x16x32_bf16(kf[1], qA1, s0, 0, 0, 0);
      s1 = __builtin_amdgcn_mfma_f32_16x16x32_bf16(kf[2], qA0, s1, 0, 0, 0);
      s1 = __builtin_amdgcn_mfma_f32_16x16x32_bf16(kf[3], qA1, s1, 0, 0, 0);
      short p0[4], p1[4];
      #pragma unroll
      for (int r = 0; r < 4; ++r) {
        float e0 = __expf(s0[r] + btA[0] + bp4[r]);
        float e1 = __expf(s1[r] + btA[1] + bp4[r]);
        psA += e0 + e1;
        p0[r] = f2b(e0); p1[r] = f2b(e1);
      }
      b16x4 pf0 = *(b16x4*)p0, pf1 = *(b16x4*)p1;
      #pragma unroll
      for (int nt = 0; nt < 4; ++nt) {
        oA[nt] = __builtin_amdgcn_mfma_f32_16x16x16bf16_1k(pf0, vf[0][nt], oA[nt], 0, 0, 0);
        oA[nt] = __builtin_amdgcn_mfma_f32_16x16x16bf16_1k(pf1, vf[1][nt], oA[nt], 0, 0, 0);
      }
    }

    #pragma unroll
    for (int i = 0; i < 4; ++i) kf[i] = nkf[i];
    #pragma unroll
    for (int t = 0; t < 2; ++t) {
      #pragma unroll
      for (int nt = 0; nt < 4; ++nt) vf[t][nt] = nvf[t][nt];
      btA[t] = nbtA[t]; btB[t] = nbtB[t];
    }
  }
  #undef BT

  // psum: reduce over quads (all kn held across quad groups), lane n16 = qn
  psA += __shfl_xor(psA, 16); psA += __shfl_xor(psA, 32);
  psB += __shfl_xor(psB, 16); psB += __shfl_xor(psB, 32);

  // O rows are qn = quad*4+r; fetch that qn's sum from lane (quad*4+r)
  #pragma unroll
  for (int nt = 0; nt < 4; ++nt) {
    int c = h * 64 + nt * 16 + n16;   // n16 = d_local here (PV C-layout col)
    #pragma unroll
    for (int r = 0; r < 4; ++r) {
      int qn = quad * 4 + r;
      float iA = 1.0f / __shfl(psA, qn);
      float iB = 1.0f / __shfl(psB, qn);
      yatt[((size_t)b * 768 + qn * 48 + qtA) * 512 + c] = f2b(oA[nt][r] * iA);
      yatt[((size_t)b * 768 + qn * 48 + qtB) * 512 + c] = f2b(oB[nt][r] * iB);
    }
  }
}

// ---------------------------------------------------------------------------
// proj: yatt(12288x512,bf16) @ WoT -> out fp32
// ---------------------------------------------------------------------------
__global__ __launch_bounds__(256) void proj_kernel(
    const short* __restrict__ yatt, const short* __restrict__ WT,
    float* __restrict__ out)
{
  __shared__ short As[128][32];
  __shared__ short Bs[128][32];
  int tid = threadIdx.x;
  int w = tid >> 6, lane = tid & 63, n16 = lane & 15, quad = lane >> 4;
  int row0 = blockIdx.x * 128;
  int ncol0 = blockIdx.y * 128;
  const short* Wt = WT + (size_t)3 * 262144;

  f32x4 zero4 = {0.f, 0.f, 0.f, 0.f};
  f32x4 acc[4][4];
  #pragma unroll
  for (int mt = 0; mt < 4; ++mt)
    #pragma unroll
    for (int nt = 0; nt < 4; ++nt) acc[mt][nt] = zero4;

  int srow = tid >> 1, sch = (tid & 1) * 16;
  const short* ga = yatt + (size_t)(row0 + srow) * 512 + sch;
  const short* gb = Wt + (size_t)(ncol0 + srow) * 512 + sch;
  int wm = (w >> 1) * 64, wn = (w & 1) * 64;

  for (int kt = 0; kt < 16; ++kt) {
    b16x8 a0 = *(const b16x8*)(ga);
    b16x8 a1 = *(const b16x8*)(ga + 8);
    b16x8 b0 = *(const b16x8*)(gb);
    b16x8 b1 = *(const b16x8*)(gb + 8);
    ga += 32; gb += 32;
    __syncthreads();
    *(b16x8*)&As[srow][sch]     = a0;
    *(b16x8*)&As[srow][sch + 8] = a1;
    *(b16x8*)&Bs[srow][sch]     = b0;
    *(b16x8*)&Bs[srow][sch + 8] = b1;
    __syncthreads();
    b16x8 af[4], bf[4];
    #pragma unroll
    for (int mt = 0; mt < 4; ++mt) af[mt] = *(const b16x8*)&As[wm + mt * 16 + n16][quad * 8];
    #pragma unroll
    for (int nt = 0; nt < 4; ++nt) bf[nt] = *(const b16x8*)&Bs[wn + nt * 16 + n16][quad * 8];
    #pragma unroll
    for (int mt = 0; mt < 4; ++mt)
      #pragma unroll
      for (int nt = 0; nt < 4; ++nt)
        acc[mt][nt] = __builtin_amdgcn_mfma_f32_16x16x32_bf16(af[mt], bf[nt], acc[mt][nt], 0, 0, 0);
  }

  #pragma unroll
  for (int mt = 0; mt < 4; ++mt) {
    int rowb = row0 + wm + mt * 16 + quad * 4;
    #pragma unroll
    for (int nt = 0; nt < 4; ++nt) {
      int colg = ncol0 + wn + nt * 16 + n16;
      #pragma unroll
      for (int r = 0; r < 4; ++r)
        out[(size_t)(rowb + r) * 512 + colg] = acc[mt][nt][r];
    }
  }
}

// ---------------------------------------------------------------------------
extern "C" void kernel_launch(void* const* d_in, const int* in_sizes, int n_in,
                              void* d_out, int out_size, void* d_ws, size_t ws_size,
                              hipStream_t stream) {
  const float* x    = (const float*)d_in[0];
  const float* Wq   = (const float*)d_in[1];
  const float* Wk   = (const float*)d_in[2];
  const float* Wv   = (const float*)d_in[3];
  const float* Wo   = (const float*)d_in[4];
  const float* relT = (const float*)d_in[5];
  const float* relP = (const float*)d_in[6];

  char* wsb = (char*)d_ws;
  const size_t SZ = (size_t)BL_ * C_ * 2;
  short* xb  = (short*)(wsb);
  short* WT  = (short*)(wsb + SZ);
  short* qb  = (short*)(wsb + SZ + 2097152);
  short* kb  = (short*)(wsb + 2 * SZ + 2097152);
  short* vTb = (short*)(wsb + 3 * SZ + 2097152);
  short* yat = (short*)(wsb + 4 * SZ + 2097152 + 4096);

  cast_x_kernel<<<dim3(3072), dim3(256), 0, stream>>>(x, xb, BL_ * C_ / 8);
  cast_w_kernel<<<dim3(16, 16, 4), dim3(32, 8), 0, stream>>>(Wq, Wk, Wv, Wo, WT);
  qkv_kernel<<<dim3(96, 12), dim3(256), 0, stream>>>(xb, WT, qb, kb, vTb);
  attn_kernel<<<dim3(1536), dim3(128), 0, stream>>>(qb, kb, vTb, relT, relP, yat);
  proj_kernel<<<dim3(96, 4), dim3(256), 0, stream>>>(yat, WT, (float*)d_out);
}

// Round 7
// 208.953 us; speedup vs baseline: 1.2984x; 1.2984x over previous
//
#include <hip/hip_runtime.h>
#include <hip/hip_bf16.h>
#include <math.h>

#define B_  16
#define N_  16
#define T_  48
#define C_  512
#define H_  8
#define HD_ 64
#define L_  768
#define BL_ 12288

typedef __attribute__((ext_vector_type(8))) short b16x8;
typedef __attribute__((ext_vector_type(4))) float f32x4;

__device__ __forceinline__ short f2b(float f) {
  __hip_bfloat16 h = __float2bfloat16(f);
  return *reinterpret_cast<short*>(&h);
}
// fast RNE float->bf16 (no NaN handling; inputs finite)
__device__ __forceinline__ short brne(float f) {
  unsigned u = __float_as_uint(f);
  u += 0x7fffu + ((u >> 16) & 1u);
  return (short)(u >> 16);
}

// ---------------------------------------------------------------------------
// prep: blocks [0,3072) cast x fp32->bf16; blocks [3072,4096) cast+transpose
// weights into WT[mat][n][k] (Wq pre-scaled by 1/8).
// ---------------------------------------------------------------------------
__global__ __launch_bounds__(256) void prep_kernel(
    const float* __restrict__ x,
    const float* __restrict__ Wq, const float* __restrict__ Wk,
    const float* __restrict__ Wv, const float* __restrict__ Wo,
    short* __restrict__ xb, short* __restrict__ WT)
{
  __shared__ float tile[32][33];
  int blk = blockIdx.x;
  int tid = threadIdx.x;
  if (blk < 3072) {
    int i = blk * 256 + tid;
    const float4* src = (const float4*)(x + (size_t)i * 8);
    float4 a = src[0], b = src[1];
    short tmp[8] = {f2b(a.x), f2b(a.y), f2b(a.z), f2b(a.w),
                    f2b(b.x), f2b(b.y), f2b(b.z), f2b(b.w)};
    *(b16x8*)(xb + (size_t)i * 8) = *(b16x8*)tmp;
  } else {
    int idx = blk - 3072;
    int mat = idx >> 8, rem = idx & 255;
    const float* W = (mat == 0) ? Wq : (mat == 1) ? Wk : (mat == 2) ? Wv : Wo;
    float scale = (mat == 0) ? 0.125f : 1.0f;
    int k0 = (rem >> 4) * 32, n0 = (rem & 15) * 32;
    int tx = tid & 31, ty = tid >> 5;
    for (int i = ty; i < 32; i += 8) tile[i][tx] = W[(size_t)(k0 + i) * 512 + n0 + tx];
    __syncthreads();
    short* dst = WT + (size_t)mat * 262144;
    for (int i = ty; i < 32; i += 8)
      dst[(size_t)(n0 + i) * 512 + k0 + tx] = f2b(tile[tx][i] * scale);
  }
}

// ---------------------------------------------------------------------------
// QKV GEMM, time-major permuted M-rows (rr = pt*16+pn) + LDS-staged epilogue.
//   q2,k2: [b][h][t][n][d]   vT2: [b][h][d][t][n]
// ---------------------------------------------------------------------------
__global__ __launch_bounds__(256) void qkv_kernel(
    const short* __restrict__ xb, const short* __restrict__ WT,
    short* __restrict__ q2, short* __restrict__ k2, short* __restrict__ vT2)
{
  __shared__ short smem[8192];              // As/Bs during K-loop; Ls in epilogue
  short (*As)[32] = (short(*)[32])smem;
  short (*Bs)[32] = (short(*)[32])(smem + 4096);
  int tid = threadIdx.x;
  int w = tid >> 6, lane = tid & 63, n16 = lane & 15, quad = lane >> 4;
  int bm = blockIdx.x, bn = blockIdx.y;
  int mat = bn >> 2;
  int ncol0 = (bn & 3) * 128;
  const short* Wt = WT + (size_t)mat * 262144;
  int bq = bm / 6;
  int rr0 = (bm % 6) * 128;

  f32x4 zero4 = {0.f, 0.f, 0.f, 0.f};
  f32x4 acc[4][4];
  #pragma unroll
  for (int mt = 0; mt < 4; ++mt)
    #pragma unroll
    for (int nt = 0; nt < 4; ++nt) acc[mt][nt] = zero4;

  int srow = tid >> 1, sch = (tid & 1) * 16;
  int rr = rr0 + srow;
  int pt = rr >> 4, pn = rr & 15;           // permuted row -> l = pn*48+pt
  const short* ga = xb + ((size_t)bq * 768 + pn * 48 + pt) * 512 + sch;
  const short* gb = Wt + (size_t)(ncol0 + srow) * 512 + sch;
  int wm = (w >> 1) * 64, wn = (w & 1) * 64;

  for (int kt = 0; kt < 16; ++kt) {
    b16x8 a0 = *(const b16x8*)(ga);
    b16x8 a1 = *(const b16x8*)(ga + 8);
    b16x8 b0 = *(const b16x8*)(gb);
    b16x8 b1 = *(const b16x8*)(gb + 8);
    ga += 32; gb += 32;
    __syncthreads();
    *(b16x8*)&As[srow][sch]     = a0;
    *(b16x8*)&As[srow][sch + 8] = a1;
    *(b16x8*)&Bs[srow][sch]     = b0;
    *(b16x8*)&Bs[srow][sch + 8] = b1;
    __syncthreads();
    b16x8 af[4], bf[4];
    #pragma unroll
    for (int mt = 0; mt < 4; ++mt) af[mt] = *(const b16x8*)&As[wm + mt * 16 + n16][quad * 8];
    #pragma unroll
    for (int nt = 0; nt < 4; ++nt) bf[nt] = *(const b16x8*)&Bs[wn + nt * 16 + n16][quad * 8];
    #pragma unroll
    for (int mt = 0; mt < 4; ++mt)
      #pragma unroll
      for (int nt = 0; nt < 4; ++nt)
        acc[mt][nt] = __builtin_amdgcn_mfma_f32_16x16x32_bf16(af[mt], bf[nt], acc[mt][nt], 0, 0, 0);
  }

  // epilogue: 4 chunks of 32 tile-rows staged through LDS, vector stores out
  short (*Ls)[136] = (short(*)[136])smem;   // 32 x 136 (pad: aligned, spread banks)
  for (int c = 0; c < 4; ++c) {
    __syncthreads();
    if ((w >> 1) == (c >> 1)) {             // waves owning rows 32c..32c+31
      int mtb = (c & 1) * 2;
      #pragma unroll
      for (int mi = 0; mi < 2; ++mi) {
        #pragma unroll
        for (int nt = 0; nt < 4; ++nt)
          #pragma unroll
          for (int r = 0; r < 4; ++r)
            Ls[mi * 16 + quad * 4 + r][wn + nt * 16 + n16] = f2b(acc[mtb + mi][nt][r]);
      }
    }
    __syncthreads();
    int rrc = rr0 + c * 32;
    if (mat != 2) {
      short* dst = (mat == 0) ? q2 : k2;
      int row = tid >> 3, c0 = (tid & 7) * 16;
      int hhg = (ncol0 + c0) >> 6, d0 = (ncol0 + c0) & 63;
      short* dp = dst + ((size_t)(bq * 8 + hhg) * 768 + rrc + row) * 64 + d0;
      *(b16x8*)dp       = *(b16x8*)&Ls[row][c0];
      *(b16x8*)(dp + 8) = *(b16x8*)&Ls[row][c0 + 8];
    } else {
      int cp = tid & 63, r8 = (tid >> 6) * 8;
      int c0 = 2 * cp;
      int hhg = (ncol0 + c0) >> 6, d0 = (ncol0 + c0) & 63;
      short t0[8], t1[8];
      #pragma unroll
      for (int j = 0; j < 8; ++j) { t0[j] = Ls[r8 + j][c0]; t1[j] = Ls[r8 + j][c0 + 1]; }
      short* dp = vT2 + ((size_t)(bq * 8 + hhg) * 64 + d0) * 768 + rrc + r8;
      *(b16x8*)dp         = *(b16x8*)t0;
      *(b16x8*)(dp + 768) = *(b16x8*)t1;
    }
  }
}

// ---------------------------------------------------------------------------
// Attention (R5 core): time-major tiles, wave = (b,h,{qt,47-qt}), no-max
// softmax, wave-private LDS P round-trip. NEW: rotated prefetch registers
// (no loop-end copies -> loads stay in flight across a step).
// ---------------------------------------------------------------------------
__global__ __launch_bounds__(128) void attn_kernel(
    const short* __restrict__ q2, const short* __restrict__ k2,
    const short* __restrict__ vT2,
    const float* __restrict__ relT, const float* __restrict__ relP,
    short* __restrict__ yatt)
{
  __shared__ short P[2][2][2][16][40];      // [wave][band][parity][qn][K+pad]
  __shared__ float btL[2][96];

  int tid = threadIdx.x;
  int wv = tid >> 6, lane = tid & 63, n16 = lane & 15, quad = lane >> 4;
  int blk = blockIdx.x;
  int h = blk & 7;                          // XCD-locality
  int g = blk >> 3;
  int pg = g % 12, b = g / 12;
  int pair = pg * 2 + wv;
  int qtA = pair, qtB = 47 - pair;
  int nA = (qtA + 2) >> 1, nB = (qtB + 2) >> 1;

  btL[wv][lane] = relT[(lane < 95 ? lane : 94) * 8 + h];
  if (lane < 32) btL[wv][64 + lane] = relT[((64 + lane) < 95 ? 64 + lane : 94) * 8 + h];

  float bp4[4];
  #pragma unroll
  for (int r = 0; r < 4; ++r)
    bp4[r] = relP[(n16 - quad * 4 - r + 15) * 8 + h];

  size_t bh = (size_t)(b * 8 + h);
  const short* qb = q2 + bh * 49152;
  const short* kb = k2 + bh * 49152;
  const short* vb = vT2 + bh * 49152;

  b16x8 qA0 = *(const b16x8*)(qb + (qtA * 16 + n16) * 64 + quad * 8);
  b16x8 qA1 = *(const b16x8*)(qb + (qtA * 16 + n16) * 64 + quad * 8 + 32);
  b16x8 qB0 = *(const b16x8*)(qb + (qtB * 16 + n16) * 64 + quad * 8);
  b16x8 qB1 = *(const b16x8*)(qb + (qtB * 16 + n16) * 64 + quad * 8 + 32);

  f32x4 zero4 = {0.f, 0.f, 0.f, 0.f};
  f32x4 oA[4], oB[4];
  float psA[4] = {0, 0, 0, 0}, psB[4] = {0, 0, 0, 0};
  #pragma unroll
  for (int nt = 0; nt < 4; ++nt) { oA[nt] = zero4; oB[nt] = zero4; }

  b16x8 kfa[4], kfb[4];
  auto loadK = [&](int kt2, b16x8* kf) {
    const short* kp = kb + (size_t)(kt2 * 32 + n16) * 64 + quad * 8;
    kf[0] = *(const b16x8*)kp;
    kf[1] = *(const b16x8*)(kp + 32);
    kf[2] = *(const b16x8*)(kp + 1024);
    kf[3] = *(const b16x8*)(kp + 1024 + 32);
  };
  auto step = [&](int kt2, b16x8* kf) {
    int par = kt2 & 1;
    int kt0 = kt2 * 2;
    b16x8 vf[4];
    #pragma unroll
    for (int nt = 0; nt < 4; ++nt)
      vf[nt] = *(const b16x8*)(vb + (size_t)(nt * 16 + n16) * 768 + kt2 * 32 + quad * 8);
    bool doA = kt2 < nA;                    // wave-uniform
    f32x4 sB0 = zero4, sB1 = zero4, sA0 = zero4, sA1 = zero4;
    sB0 = __builtin_amdgcn_mfma_f32_16x16x32_bf16(qB0, kf[0], sB0, 0, 0, 0);
    sB0 = __builtin_amdgcn_mfma_f32_16x16x32_bf16(qB1, kf[1], sB0, 0, 0, 0);
    sB1 = __builtin_amdgcn_mfma_f32_16x16x32_bf16(qB0, kf[2], sB1, 0, 0, 0);
    sB1 = __builtin_amdgcn_mfma_f32_16x16x32_bf16(qB1, kf[3], sB1, 0, 0, 0);
    if (doA) {
      sA0 = __builtin_amdgcn_mfma_f32_16x16x32_bf16(qA0, kf[0], sA0, 0, 0, 0);
      sA0 = __builtin_amdgcn_mfma_f32_16x16x32_bf16(qA1, kf[1], sA0, 0, 0, 0);
      sA1 = __builtin_amdgcn_mfma_f32_16x16x32_bf16(qA0, kf[2], sA1, 0, 0, 0);
      sA1 = __builtin_amdgcn_mfma_f32_16x16x32_bf16(qA1, kf[3], sA1, 0, 0, 0);
    }
    float btB0 = (kt0 <= qtB) ? btL[wv][kt0 - qtB + 47] : -1e30f;
    float btB1 = (kt0 + 1 <= qtB) ? btL[wv][kt0 + 1 - qtB + 47] : -1e30f;
    #pragma unroll
    for (int r = 0; r < 4; ++r) {
      float e0 = __expf(sB0[r] + btB0 + bp4[r]);
      float e1 = __expf(sB1[r] + btB1 + bp4[r]);
      psB[r] += e0 + e1;
      P[wv][1][par][quad * 4 + r][n16]      = brne(e0);
      P[wv][1][par][quad * 4 + r][16 + n16] = brne(e1);
    }
    if (doA) {
      float btA0 = (kt0 <= qtA) ? btL[wv][kt0 - qtA + 47] : -1e30f;
      float btA1 = (kt0 + 1 <= qtA) ? btL[wv][kt0 + 1 - qtA + 47] : -1e30f;
      #pragma unroll
      for (int r = 0; r < 4; ++r) {
        float e0 = __expf(sA0[r] + btA0 + bp4[r]);
        float e1 = __expf(sA1[r] + btA1 + bp4[r]);
        psA[r] += e0 + e1;
        P[wv][0][par][quad * 4 + r][n16]      = brne(e0);
        P[wv][0][par][quad * 4 + r][16 + n16] = brne(e1);
      }
    }
    b16x8 pfB = *(const b16x8*)&P[wv][1][par][n16][quad * 8];
    #pragma unroll
    for (int nt = 0; nt < 4; ++nt)
      oB[nt] = __builtin_amdgcn_mfma_f32_16x16x32_bf16(pfB, vf[nt], oB[nt], 0, 0, 0);
    if (doA) {
      b16x8 pfA = *(const b16x8*)&P[wv][0][par][n16][quad * 8];
      #pragma unroll
      for (int nt = 0; nt < 4; ++nt)
        oA[nt] = __builtin_amdgcn_mfma_f32_16x16x32_bf16(pfA, vf[nt], oA[nt], 0, 0, 0);
    }
  };

  loadK(0, kfa);
  for (int kt2 = 0; kt2 < nB; kt2 += 2) {
    if (kt2 + 1 < nB) loadK(kt2 + 1, kfb);
    step(kt2, kfa);
    if (kt2 + 1 < nB) {
      if (kt2 + 2 < nB) loadK(kt2 + 2, kfa);
      step(kt2 + 1, kfb);
    }
  }

  #pragma unroll
  for (int r = 0; r < 4; ++r) {
    float sA = psA[r], sB = psB[r];
    sA += __shfl_xor(sA, 1); sA += __shfl_xor(sA, 2);
    sA += __shfl_xor(sA, 4); sA += __shfl_xor(sA, 8);
    sB += __shfl_xor(sB, 1); sB += __shfl_xor(sB, 2);
    sB += __shfl_xor(sB, 4); sB += __shfl_xor(sB, 8);
    psA[r] = 1.0f / sA; psB[r] = 1.0f / sB;
  }
  #pragma unroll
  for (int nt = 0; nt < 4; ++nt) {
    int c = h * 64 + nt * 16 + n16;
    #pragma unroll
    for (int r = 0; r < 4; ++r) {
      int qn = quad * 4 + r;
      yatt[((size_t)b * 768 + qn * 48 + qtA) * 512 + c] = f2b(oA[nt][r] * psA[r]);
      yatt[((size_t)b * 768 + qn * 48 + qtB) * 512 + c] = f2b(oB[nt][r] * psB[r]);
    }
  }
}

// ---------------------------------------------------------------------------
// proj: yatt(12288x512,bf16) @ WoT -> out fp32
// ---------------------------------------------------------------------------
__global__ __launch_bounds__(256) void proj_kernel(
    const short* __restrict__ yatt, const short* __restrict__ WT,
    float* __restrict__ out)
{
  __shared__ short As[128][32];
  __shared__ short Bs[128][32];
  int tid = threadIdx.x;
  int w = tid >> 6, lane = tid & 63, n16 = lane & 15, quad = lane >> 4;
  int row0 = blockIdx.x * 128;
  int ncol0 = blockIdx.y * 128;
  const short* Wt = WT + (size_t)3 * 262144;

  f32x4 zero4 = {0.f, 0.f, 0.f, 0.f};
  f32x4 acc[4][4];
  #pragma unroll
  for (int mt = 0; mt < 4; ++mt)
    #pragma unroll
    for (int nt = 0; nt < 4; ++nt) acc[mt][nt] = zero4;

  int srow = tid >> 1, sch = (tid & 1) * 16;
  const short* ga = yatt + (size_t)(row0 + srow) * 512 + sch;
  const short* gb = Wt + (size_t)(ncol0 + srow) * 512 + sch;
  int wm = (w >> 1) * 64, wn = (w & 1) * 64;

  for (int kt = 0; kt < 16; ++kt) {
    b16x8 a0 = *(const b16x8*)(ga);
    b16x8 a1 = *(const b16x8*)(ga + 8);
    b16x8 b0 = *(const b16x8*)(gb);
    b16x8 b1 = *(const b16x8*)(gb + 8);
    ga += 32; gb += 32;
    __syncthreads();
    *(b16x8*)&As[srow][sch]     = a0;
    *(b16x8*)&As[srow][sch + 8] = a1;
    *(b16x8*)&Bs[srow][sch]     = b0;
    *(b16x8*)&Bs[srow][sch + 8] = b1;
    __syncthreads();
    b16x8 af[4], bf[4];
    #pragma unroll
    for (int mt = 0; mt < 4; ++mt) af[mt] = *(const b16x8*)&As[wm + mt * 16 + n16][quad * 8];
    #pragma unroll
    for (int nt = 0; nt < 4; ++nt) bf[nt] = *(const b16x8*)&Bs[wn + nt * 16 + n16][quad * 8];
    #pragma unroll
    for (int mt = 0; mt < 4; ++mt)
      #pragma unroll
      for (int nt = 0; nt < 4; ++nt)
        acc[mt][nt] = __builtin_amdgcn_mfma_f32_16x16x32_bf16(af[mt], bf[nt], acc[mt][nt], 0, 0, 0);
  }

  #pragma unroll
  for (int mt = 0; mt < 4; ++mt) {
    int rowb = row0 + wm + mt * 16 + quad * 4;
    #pragma unroll
    for (int nt = 0; nt < 4; ++nt) {
      int colg = ncol0 + wn + nt * 16 + n16;
      #pragma unroll
      for (int r = 0; r < 4; ++r)
        out[(size_t)(rowb + r) * 512 + colg] = acc[mt][nt][r];
    }
  }
}

// ---------------------------------------------------------------------------
extern "C" void kernel_launch(void* const* d_in, const int* in_sizes, int n_in,
                              void* d_out, int out_size, void* d_ws, size_t ws_size,
                              hipStream_t stream) {
  const float* x    = (const float*)d_in[0];
  const float* Wq   = (const float*)d_in[1];
  const float* Wk   = (const float*)d_in[2];
  const float* Wv   = (const float*)d_in[3];
  const float* Wo   = (const float*)d_in[4];
  const float* relT = (const float*)d_in[5];
  const float* relP = (const float*)d_in[6];

  char* wsb = (char*)d_ws;
  const size_t SZ = (size_t)BL_ * C_ * 2;
  short* xb  = (short*)(wsb);
  short* WT  = (short*)(wsb + SZ);
  short* qb  = (short*)(wsb + SZ + 2097152);
  short* kb  = (short*)(wsb + 2 * SZ + 2097152);
  short* vTb = (short*)(wsb + 3 * SZ + 2097152);
  short* yat = (short*)(wsb + 4 * SZ + 2097152 + 4096);

  prep_kernel<<<dim3(4096), dim3(256), 0, stream>>>(x, Wq, Wk, Wv, Wo, xb, WT);
  qkv_kernel<<<dim3(96, 12), dim3(256), 0, stream>>>(xb, WT, qb, kb, vTb);
  attn_kernel<<<dim3(1536), dim3(128), 0, stream>>>(qb, kb, vTb, relT, relP, yat);
  proj_kernel<<<dim3(96, 4), dim3(256), 0, stream>>>(yat, WT, (float*)d_out);
}